// Round 1
// baseline (100.736 us; speedup 1.0000x reference)
//
#include <hip/hip_runtime.h>

// Problem constants (from reference): x [B=32, C=256, H=128, W=128] f32
#define BATCH 32
#define CH    256
#define HH    128
#define WW    128
#define HW    (HH * WW)        // 16384
#define HW4   (HW / 4)         // 4096

// Kernel 1: per-spatial-position channel mean+max.
// One thread handles 4 consecutive spatial positions via float4.
// Writes red[b][0][hw] = mean, red[b][1][hw] = max  (layout [B,2,H,W]).
__global__ __launch_bounds__(256) void reduce_mean_max(
    const float* __restrict__ x, float* __restrict__ red) {
    int idx = blockIdx.x * blockDim.x + threadIdx.x;   // [0, B*HW4)
    int b  = idx >> 12;      // / HW4
    int p4 = idx & (HW4 - 1);

    const float4* xp = reinterpret_cast<const float4*>(x)
                       + (size_t)b * (size_t)CH * HW4 + p4;

    float4 v = xp[0];
    float4 s = v;
    float4 m = v;
    #pragma unroll 8
    for (int c = 1; c < CH; ++c) {
        float4 t = xp[(size_t)c * HW4];
        s.x += t.x; s.y += t.y; s.z += t.z; s.w += t.w;
        m.x = fmaxf(m.x, t.x);
        m.y = fmaxf(m.y, t.y);
        m.z = fmaxf(m.z, t.z);
        m.w = fmaxf(m.w, t.w);
    }

    const float inv = 1.0f / (float)CH;
    float4 avg = make_float4(s.x * inv, s.y * inv, s.z * inv, s.w * inv);

    float4* rp = reinterpret_cast<float4*>(red) + (size_t)b * (2 * HW4) + p4;
    rp[0]   = avg;   // channel 0: mean
    rp[HW4] = m;     // channel 1: max
}

// Kernel 2: 3x3 conv (2->1 ch, pad 1, OIHW weights) + SiLU, one thread/pixel.
__global__ __launch_bounds__(256) void conv3x3_silu(
    const float* __restrict__ red, const float* __restrict__ cw,
    float* __restrict__ out) {
    int idx = blockIdx.x * blockDim.x + threadIdx.x;   // [0, B*HW)
    int b  = idx >> 14;          // / HW
    int hw = idx & (HW - 1);
    int h  = hw >> 7;            // / WW
    int w  = hw & (WW - 1);

    float wreg[18];
    #pragma unroll
    for (int i = 0; i < 18; ++i) wreg[i] = cw[i];   // broadcast, L1-served

    const float* base = red + (size_t)b * (2 * HW);
    float acc = 0.0f;
    #pragma unroll
    for (int ic = 0; ic < 2; ++ic) {
        #pragma unroll
        for (int kh = 0; kh < 3; ++kh) {
            int ih = h + kh - 1;
            if (ih < 0 || ih >= HH) continue;
            #pragma unroll
            for (int kw = 0; kw < 3; ++kw) {
                int iw = w + kw - 1;
                if (iw < 0 || iw >= WW) continue;
                acc += base[ic * HW + ih * WW + iw] * wreg[ic * 9 + kh * 3 + kw];
            }
        }
    }
    // SiLU: y * sigmoid(y)
    out[idx] = acc / (1.0f + expf(-acc));
}

extern "C" void kernel_launch(void* const* d_in, const int* in_sizes, int n_in,
                              void* d_out, int out_size, void* d_ws, size_t ws_size,
                              hipStream_t stream) {
    const float* x  = (const float*)d_in[0];   // [32,256,128,128] f32
    const float* cw = (const float*)d_in[1];   // [1,2,3,3] f32
    float* out = (float*)d_out;                // [32,1,128,128] f32
    float* red = (float*)d_ws;                 // [32,2,128,128] f32 = 4 MiB

    // Kernel 1: B*HW4 = 131072 threads
    reduce_mean_max<<<(BATCH * HW4) / 256, 256, 0, stream>>>(x, red);
    // Kernel 2: B*HW = 524288 threads
    conv3x3_silu<<<(BATCH * HW) / 256, 256, 0, stream>>>(red, cw, out);
}

// Round 3
// 94.706 us; speedup vs baseline: 1.0637x; 1.0637x over previous
//
#include <hip/hip_runtime.h>

// x [B=32, C=256, H=128, W=128] f32; conv_w [1,2,3,3] f32
#define BATCH 32
#define CH    256
#define HH    128
#define WW    128
#define HW    (HH * WW)        // 16384
#define HW4   (HW / 4)         // 4096

typedef float f32x4 __attribute__((ext_vector_type(4)));

// Kernel 1: per-spatial-position channel mean+max.
// One thread handles 4 consecutive spatial positions via float4 (nontemporal).
// red layout: [B][2][H][W]  (ch0 = mean, ch1 = max)
__global__ __launch_bounds__(256) void reduce_mean_max(
    const float* __restrict__ x, float* __restrict__ red) {
    int idx = blockIdx.x * blockDim.x + threadIdx.x;   // [0, B*HW4)
    int b  = idx >> 12;      // / HW4
    int p4 = idx & (HW4 - 1);

    const f32x4* xp = reinterpret_cast<const f32x4*>(x)
                      + (size_t)b * (size_t)CH * HW4 + p4;

    f32x4 s = {0.f, 0.f, 0.f, 0.f};
    f32x4 m = {-INFINITY, -INFINITY, -INFINITY, -INFINITY};
    #pragma unroll 16
    for (int c = 0; c < CH; ++c) {
        f32x4 t = __builtin_nontemporal_load(xp + (size_t)c * HW4);
        s += t;
        m.x = fmaxf(m.x, t.x);
        m.y = fmaxf(m.y, t.y);
        m.z = fmaxf(m.z, t.z);
        m.w = fmaxf(m.w, t.w);
    }

    const float inv = 1.0f / (float)CH;
    f32x4 avg = s * inv;

    f32x4* rp = reinterpret_cast<f32x4*>(red) + (size_t)b * (2 * HW4) + p4;
    rp[0]   = avg;   // channel 0: mean
    rp[HW4] = m;     // channel 1: max
}

// Kernel 2: 3x3 conv (2->1 ch, pad 1, OIHW weights) + SiLU.
// Block = 8 output rows of one image; LDS tile [2][10][130] (zero-padded
// width), coalesced float4 staging, each thread computes 4 pixels.
#define TROWS 8
#define LW    (WW + 2)    // 130, padded row

__global__ __launch_bounds__(256) void conv3x3_silu(
    const float* __restrict__ red, const float* __restrict__ cw,
    float* __restrict__ out) {
    __shared__ float lin[2][TROWS + 2][LW];   // 2*10*130*4 = 10.4 KB

    int blk = blockIdx.x;            // 32*16 = 512 blocks
    int b   = blk >> 4;
    int r0  = (blk & 15) * TROWS;
    int tid = threadIdx.x;

    // zero the two pad columns (20 row-channel pairs)
    if (tid < 2 * (TROWS + 2)) {
        int ch  = tid / (TROWS + 2);
        int row = tid - ch * (TROWS + 2);
        lin[ch][row][0]      = 0.f;
        lin[ch][row][LW - 1] = 0.f;
    }

    // stage 2 ch x 10 rows x 128 cols = 640 float4 loads, coalesced
    const float4* red4 = reinterpret_cast<const float4*>(red);
    for (int l = tid; l < 640; l += 256) {
        int ch  = l / 320;
        int rem = l - ch * 320;
        int row = rem >> 5;          // 0..9
        int c4  = rem & 31;          // 0..31
        int gr  = r0 - 1 + row;
        float4 v = make_float4(0.f, 0.f, 0.f, 0.f);
        if (gr >= 0 && gr < HH)
            v = red4[((size_t)b * 2 + ch) * HW4 + gr * 32 + c4];
        float* dst = &lin[ch][row][1 + 4 * c4];
        dst[0] = v.x; dst[1] = v.y; dst[2] = v.z; dst[3] = v.w;
    }

    float wg[18];
    #pragma unroll
    for (int i = 0; i < 18; ++i) wg[i] = cw[i];   // uniform -> s_loads

    __syncthreads();

    int lr = tid >> 5;               // 0..7  (output row within tile)
    int w0 = (tid & 31) * 4;         // 0..124 (first output col)

    float acc[4] = {0.f, 0.f, 0.f, 0.f};
    #pragma unroll
    for (int ch = 0; ch < 2; ++ch) {
        #pragma unroll
        for (int dr = 0; dr < 3; ++dr) {
            const float* rowp = &lin[ch][lr + dr][w0];  // [w0-1..w0+4] padded
            float e[6];
            #pragma unroll
            for (int k = 0; k < 6; ++k) e[k] = rowp[k];
            const float* wp = &wg[ch * 9 + dr * 3];
            #pragma unroll
            for (int j = 0; j < 4; ++j)
                acc[j] += e[j] * wp[0] + e[j + 1] * wp[1] + e[j + 2] * wp[2];
        }
    }

    float4 o;
    o.x = acc[0] / (1.f + expf(-acc[0]));
    o.y = acc[1] / (1.f + expf(-acc[1]));
    o.z = acc[2] / (1.f + expf(-acc[2]));
    o.w = acc[3] / (1.f + expf(-acc[3]));
    reinterpret_cast<float4*>(out)[(size_t)b * HW4 + (r0 + lr) * 32 + (w0 >> 2)] = o;
}

extern "C" void kernel_launch(void* const* d_in, const int* in_sizes, int n_in,
                              void* d_out, int out_size, void* d_ws, size_t ws_size,
                              hipStream_t stream) {
    const float* x  = (const float*)d_in[0];   // [32,256,128,128] f32
    const float* cw = (const float*)d_in[1];   // [1,2,3,3] f32
    float* out = (float*)d_out;                // [32,1,128,128] f32
    float* red = (float*)d_ws;                 // [32,2,128,128] f32 = 4 MiB

    reduce_mean_max<<<(BATCH * HW4) / 256, 256, 0, stream>>>(x, red);
    conv3x3_silu<<<BATCH * (HH / TROWS), 256, 0, stream>>>(red, cw, out);
}